// Round 13
// baseline (190.394 us; speedup 1.0000x reference)
//
#include <hip/hip_runtime.h>

#define B_ 4
#define T_ 4096
#define DM 512
#define DH 64
#define NST 256    // 16-row strips per batch

typedef short short8 __attribute__((ext_vector_type(8)));
typedef short bf16x4 __attribute__((ext_vector_type(4)));
typedef float f32x4 __attribute__((ext_vector_type(4)));
typedef float float8 __attribute__((ext_vector_type(8)));

__device__ inline short f2bf(float f) {
    unsigned u = __float_as_uint(f);
    u += 0x7fffu + ((u >> 16) & 1u);
    return (short)(u >> 16);
}
__device__ inline float bf2f(short s) {
    return __uint_as_float(((unsigned)(unsigned short)s) << 16);
}
__device__ inline short8 cvt8(const float* p) {
    float8 v = *(const float8*)p;
    short8 r;
#pragma unroll
    for (int j = 0; j < 8; j++) r[j] = f2bf(v[j]);
    return r;
}
__device__ inline unsigned cvt_pk_bf16(float a, float b) {
    unsigned r;
    asm("v_cvt_pk_bf16_f32 %0, %1, %2" : "=v"(r) : "v"(a), "v"(b));
    return r;
}
// exp+causal-mask a swapped-QK^T result column and pack to the 16x16x16 A-fragment
__device__ inline bf16x4 pmask4(f32x4 d, int sbase, int t) {
    float p[4];
#pragma unroll
    for (int r = 0; r < 4; r++) {
        float e = __expf(d[r] * 0.125f);
        p[r] = (sbase + r <= t) ? e : 0.f;
    }
    union { unsigned u[2]; bf16x4 v; } z;
    z.u[0] = cvt_pk_bf16(p[0], p[1]);
    z.u[1] = cvt_pk_bf16(p[2], p[3]);
    return z.v;
}

// ---------------- Kernel 1: q,k,v projections — LDS-staged x and fp32 W (verified body) ----------------
__global__ __launch_bounds__(256, 4) void k_proj(
    const float* __restrict__ x, const float* __restrict__ Wq,
    const float* __restrict__ Wk, const float* __restrict__ Wv,
    short* __restrict__ qb, short* __restrict__ kb, short* __restrict__ vb)
{
    __shared__ short Xs[16 * 72];    // 16 t-rows x (64+8 pad) k  = 2304 B
    __shared__ short Ws[192 * 72];   // 192 h-rows x (64+8 pad) k = 27648 B
    int tid = threadIdx.x;
    int lane = tid & 63, w = tid >> 6;
    int l16 = lane & 15, quad = lane >> 4;
    int b = blockIdx.x >> 8;
    int tile = blockIdx.x & 255;
    int t0 = tile * 16;
    long xbase = ((long)(b * T_ + t0)) * DM;
    int hb = w * 3;

    f32x4 acc[3];
#pragma unroll
    for (int i = 0; i < 3; i++) acc[i] = (f32x4)(0.f);

    for (int kc = 0; kc < DM; kc += 64) {
        if (tid < 128) {
            int row = tid >> 3, col = (tid & 7) * 8;
            *(short8*)(Xs + row * 72 + col) = cvt8(x + xbase + (long)row * DM + kc + col);
        }
#pragma unroll
        for (int p = 0; p < 6; p++) {
            int idx = p * 256 + tid;
            int row = idx >> 3, col = (idx & 7) * 8;
            const float* Wsrc = (p < 2) ? Wq : (p < 4) ? Wk : Wv;
            *(short8*)(Ws + row * 72 + col) = cvt8(Wsrc + (long)(row & 63) * DM + kc + col);
        }
        __syncthreads();
#pragma unroll
        for (int ks = 0; ks < 2; ks++) {
            short8 af = *(const short8*)(Xs + l16 * 72 + ks * 32 + quad * 8);
#pragma unroll
            for (int j = 0; j < 3; j++) {
                short8 bf = *(const short8*)(Ws + ((hb + j) * 16 + l16) * 72 + ks * 32 + quad * 8);
                acc[j] = __builtin_amdgcn_mfma_f32_16x16x32_bf16(af, bf, acc[j], 0, 0, 0);
            }
        }
        __syncthreads();
    }
#pragma unroll
    for (int j = 0; j < 3; j++) {
        int hh = hb + j, m = hh >> 2, h4 = hh & 3;
        short* outp = (m == 0) ? qb : (m == 1) ? kb : vb;
#pragma unroll
        for (int r4 = 0; r4 < 4; r4++) {
            int t = t0 + quad * 4 + r4;
            outp[((long)(b * T_ + t)) * DH + h4 * 16 + l16] = f2bf(acc[j][r4]);
        }
    }
}

// ---------------- Kernel 2: column sums — strip-exclusive, 4-wave split, no atomics ----------------
// grid = B*256 x 256 thr. Block owns s-strip rs (16 rows). 4 waves take contiguous quarters
// of the t-tile range [rs,256); all loads inside the loop (no prefetch, no reads on empty
// ranges); combine via 256B LDS; lsum plain-stored once. Longest strips (rs=0) first.
__global__ __launch_bounds__(256) void k_stats(
    const short* __restrict__ qb, const short* __restrict__ kb, float* __restrict__ lsum)
{
    __shared__ float partS[64];          // [wave][s-row 0..15]
    int tid = threadIdx.x;
    int lane = tid & 63, w = tid >> 6;
    int l16 = lane & 15, quad = lane >> 4;
    int b = blockIdx.x & 3;
    int rs = blockIdx.x >> 2;            // ascending: longest (rs=0) first
    int s0 = rs * 16;
    long bq = (long)b * T_ * DH;

    const short8* kp = (const short8*)(kb + bq + (long)(s0 + l16) * DH + quad * 8);
    short8 a0 = kp[0], a1 = kp[4];       // A[m=s][k=h]

    int n = NST - rs;                    // t-tiles rs..255
    int len = (n + 3) >> 2;
    int off_hi = (w + 1) * len; if (off_hi > n) off_hi = n;
    int jlo = rs + w * len;
    int jhi = rs + off_hi;

    float acc[4] = {0.f, 0.f, 0.f, 0.f};
    for (int j = jlo; j < jhi; j++) {
        const short8* qp = (const short8*)(qb + bq + (long)(j * 16 + l16) * DH + quad * 8);
        short8 q0 = qp[0], q1 = qp[4];   // B[n=t][k=h]
        f32x4 d = (f32x4)(0.f);
        d = __builtin_amdgcn_mfma_f32_16x16x32_bf16(a0, q0, d, 0, 0, 0);
        d = __builtin_amdgcn_mfma_f32_16x16x32_bf16(a1, q1, d, 0, 0, 0);
        int t = j * 16 + l16;
#pragma unroll
        for (int r = 0; r < 4; r++) {    // D: row=s (quad*4+r), col=t (l16)
            int s = s0 + quad * 4 + r;
            float p = __expf(d[r] * 0.125f);
            acc[r] += (t >= s) ? p : 0.f;
        }
    }
#pragma unroll
    for (int r = 0; r < 4; r++) {
        float v = acc[r];
        v += __shfl_xor(v, 1, 16); v += __shfl_xor(v, 2, 16);
        v += __shfl_xor(v, 4, 16); v += __shfl_xor(v, 8, 16);
        if (l16 == 0) partS[w * 16 + quad * 4 + r] = v;
    }
    __syncthreads();
    if (tid < 16)
        lsum[b * T_ + s0 + tid] =
            partS[tid] + partS[16 + tid] + partS[32 + tid] + partS[48 + tid];
}

// ---------------- Kernel 3: vTc[b][s/16][h][s%16] = bf16(v[b][s][h] / lsum[s]) ----------------
__global__ __launch_bounds__(256) void k_vt(
    const short* __restrict__ vb, const float* __restrict__ lsum, short* __restrict__ vTc)
{
    int tid = threadIdx.x;
    int b = blockIdx.x >> 6;
    int s0 = (blockIdx.x & 63) * 64;
    int h = tid & 63, g = tid >> 6;
    long vbase = ((long)(b * T_) + s0 + g * 16) * DH + h;
    long lbase = (long)b * T_ + s0 + g * 16;
    short8 lo, hi;
#pragma unroll
    for (int k2 = 0; k2 < 8; k2++) {
        float rl = 1.0f / lsum[lbase + k2];
        lo[k2] = f2bf(bf2f(vb[vbase + (long)k2 * DH]) * rl);
        float rh = 1.0f / lsum[lbase + 8 + k2];
        hi[k2] = f2bf(bf2f(vb[vbase + (long)(8 + k2) * DH]) * rh);
    }
    long ob = ((long)(b * 256 + (s0 >> 4) + g) * 64 + h) * 16;
    *(short8*)(vTc + ob) = lo;
    *(short8*)(vTc + ob + 8) = hi;
}

// ---------------- Kernel 4: fused score+PV — strip-exclusive, 4-wave split, no atomics ----------------
// grid = B*256 x 256 thr. Block owns t-strip r (16 rows). 4 waves take contiguous quarters
// of the s-tile range [0,r+1); all loads inside the loop; combine via 16KB LDS; out
// plain-stored exactly once. Longest strips (r=255) first.
__global__ __launch_bounds__(256) void k_out(
    const short* __restrict__ qb, const short* __restrict__ kb,
    const short* __restrict__ vTc, float* __restrict__ out)
{
    __shared__ float part[256 * 16];     // [tid][16] partials, 16 KB
    int tid = threadIdx.x;
    int lane = tid & 63, w = tid >> 6;
    int l16 = lane & 15, quad = lane >> 4;
    int b = blockIdx.x & 3;
    int r = (NST - 1) - (blockIdx.x >> 2);   // descending: longest first
    int t0 = r * 16;
    long bq = (long)b * T_ * DH;

    const short8* qp = (const short8*)(qb + bq + (long)(t0 + l16) * DH + quad * 8);
    short8 q0 = qp[0], q1 = qp[4];       // B[n=t][k=h]
    const short* vTb = vTc + (long)b * (T_ / 16) * DH * 16;
    int t = t0 + l16;

    int n = r + 1;                       // s-tiles 0..r
    int len = (n + 3) >> 2;
    int off_hi = (w + 1) * len; if (off_hi > n) off_hi = n;
    int jlo = w * len;
    int jhi = off_hi;

    f32x4 o[4];
#pragma unroll
    for (int i = 0; i < 4; i++) o[i] = (f32x4)(0.f);

    for (int j = jlo; j < jhi; j++) {
        const short8* kp = (const short8*)(kb + bq + (long)(j * 16 + l16) * DH + quad * 8);
        short8 a0 = kp[0], a1 = kp[4];   // A[m=s][k=h]
        f32x4 d = (f32x4)(0.f);
        d = __builtin_amdgcn_mfma_f32_16x16x32_bf16(a0, q0, d, 0, 0, 0);
        d = __builtin_amdgcn_mfma_f32_16x16x32_bf16(a1, q1, d, 0, 0, 0);
        bf16x4 pa = pmask4(d, j * 16 + quad * 4, t);   // lane: P[t=l16][s=quad*4+e]
        const short* vc = vTb + (long)j * 1024 + quad * 4;
#pragma unroll
        for (int h4 = 0; h4 < 4; h4++) {
            bf16x4 bv = *(const bf16x4*)(vc + (h4 * 16 + l16) * 16);  // B[n=h][k=s]
            o[h4] = __builtin_amdgcn_mfma_f32_16x16x16bf16_1k(pa, bv, o[h4], 0, 0, 0);
        }
    }

    // per-thread exclusive partial slots; wave 0 sums the 4 waves and stores
#pragma unroll
    for (int h4 = 0; h4 < 4; h4++)
#pragma unroll
        for (int rr = 0; rr < 4; rr++)
            part[tid * 16 + h4 * 4 + rr] = o[h4][rr];
    __syncthreads();
    if (w == 0) {
#pragma unroll
        for (int h4 = 0; h4 < 4; h4++)
#pragma unroll
            for (int rr = 0; rr < 4; rr++) {   // D: row=t (quad*4+rr), col=h (l16)
                int e = h4 * 4 + rr;
                float s = part[lane * 16 + e] + part[(64 + lane) * 16 + e]
                        + part[(128 + lane) * 16 + e] + part[(192 + lane) * 16 + e];
                int tt = t0 + quad * 4 + rr;
                out[bq + (long)tt * DH + h4 * 16 + l16] = s;
            }
    }
}

extern "C" void kernel_launch(void* const* d_in, const int* in_sizes, int n_in,
                              void* d_out, int out_size, void* d_ws, size_t ws_size,
                              hipStream_t stream) {
    const float* x  = (const float*)d_in[0];
    const float* Wq = (const float*)d_in[1];
    const float* Wk = (const float*)d_in[2];
    const float* Wv = (const float*)d_in[3];
    float* out = (float*)d_out;

    char* ws = (char*)d_ws;
    short* qb   = (short*)(ws);                    // 2 MB  bf16 [B,T,64]
    short* kb   = (short*)(ws + (2l << 20));       // 2 MB  bf16 [B,T,64]
    short* vb   = (short*)(ws + (4l << 20));       // 2 MB  bf16 [B,T,64]
    short* vTc  = (short*)(ws + (6l << 20));       // 2 MB  bf16 [B,T/16,64,16]
    float* lsum = (float*)(ws + (8l << 20));       // 64 KB fp32 [B,T]

    // 4 dispatches; no memsets, no atomics — all outputs plain-stored exactly once.
    k_proj<<<dim3(B_ * T_ / 16), dim3(256), 0, stream>>>(x, Wq, Wk, Wv, qb, kb, vb);
    k_stats<<<dim3(B_ * NST), dim3(256), 0, stream>>>(qb, kb, lsum);
    k_vt<<<dim3(B_ * T_ / 64), dim3(256), 0, stream>>>(vb, lsum, vTc);
    k_out<<<dim3(B_ * NST), dim3(256), 0, stream>>>(qb, kb, vTc, out);
}

// Round 14
// 143.834 us; speedup vs baseline: 1.3237x; 1.3237x over previous
//
#include <hip/hip_runtime.h>

#define B_ 4
#define T_ 4096
#define DM 512
#define DH 64
#define CS 512     // s-chunk for k_out
#define CTS 512    // t-chunk for k_stats
#define NTASK 144  // active (strip,chunk) pairs per batch for each triangle kernel

typedef short short8 __attribute__((ext_vector_type(8)));
typedef short bf16x4 __attribute__((ext_vector_type(4)));
typedef float f32x4 __attribute__((ext_vector_type(4)));
typedef float float8 __attribute__((ext_vector_type(8)));

__device__ inline short f2bf(float f) {
    unsigned u = __float_as_uint(f);
    u += 0x7fffu + ((u >> 16) & 1u);
    return (short)(u >> 16);
}
__device__ inline float bf2f(short s) {
    return __uint_as_float(((unsigned)(unsigned short)s) << 16);
}
__device__ inline short8 cvt8(const float* p) {
    float8 v = *(const float8*)p;
    short8 r;
#pragma unroll
    for (int j = 0; j < 8; j++) r[j] = f2bf(v[j]);
    return r;
}
__device__ inline unsigned cvt_pk_bf16(float a, float b) {
    unsigned r;
    asm("v_cvt_pk_bf16_f32 %0, %1, %2" : "=v"(r) : "v"(a), "v"(b));
    return r;
}
// exp+causal-mask a swapped-QK^T result column and pack to the 16x16x16 A-fragment
__device__ inline bf16x4 pmask4(f32x4 d, int sbase, int t) {
    float p[4];
#pragma unroll
    for (int r = 0; r < 4; r++) {
        float e = __expf(d[r] * 0.125f);
        p[r] = (sbase + r <= t) ? e : 0.f;
    }
    union { unsigned u[2]; bf16x4 v; } z;
    z.u[0] = cvt_pk_bf16(p[0], p[1]);
    z.u[1] = cvt_pk_bf16(p[2], p[3]);
    return z.v;
}

// ---------------- Kernel 1: q,k,v projections — W staged direct from fp32 (R9 body) ----------------
// grid = B*T/16 = 1024 blocks; also zeroes lsum (runs strictly before k_stats).
__global__ __launch_bounds__(256, 4) void k_proj(
    const float* __restrict__ x, const float* __restrict__ Wq,
    const float* __restrict__ Wk, const float* __restrict__ Wv,
    short* __restrict__ qb, short* __restrict__ kb, short* __restrict__ vb,
    float* __restrict__ lsum)
{
    __shared__ short Xs[16 * 72];    // 16 t-rows x (64+8 pad) k  = 2304 B
    __shared__ short Ws[192 * 72];   // 192 h-rows x (64+8 pad) k = 27648 B
    int tid = threadIdx.x;
    int lane = tid & 63, w = tid >> 6;
    int l16 = lane & 15, quad = lane >> 4;
    int b = blockIdx.x >> 8;         // 256 tiles per batch
    int tile = blockIdx.x & 255;
    int t0 = tile * 16;
    long xbase = ((long)(b * T_ + t0)) * DM;
    int hb = w * 3;                  // wave handles hh = hb..hb+2

    // fold-in: zero lsum (16384 floats / 1024 blocks = 16 per block)
    if (tid < 16) lsum[blockIdx.x * 16 + tid] = 0.f;

    f32x4 acc[3];
#pragma unroll
    for (int i = 0; i < 3; i++) acc[i] = (f32x4)(0.f);

    for (int kc = 0; kc < DM; kc += 64) {
        if (tid < 128) {
            int row = tid >> 3, col = (tid & 7) * 8;
            *(short8*)(Xs + row * 72 + col) = cvt8(x + xbase + (long)row * DM + kc + col);
        }
#pragma unroll
        for (int p = 0; p < 6; p++) {
            int idx = p * 256 + tid;
            int row = idx >> 3, col = (idx & 7) * 8;
            const float* Wsrc = (p < 2) ? Wq : (p < 4) ? Wk : Wv;
            *(short8*)(Ws + row * 72 + col) = cvt8(Wsrc + (long)(row & 63) * DM + kc + col);
        }
        __syncthreads();
#pragma unroll
        for (int ks = 0; ks < 2; ks++) {
            short8 af = *(const short8*)(Xs + l16 * 72 + ks * 32 + quad * 8);
#pragma unroll
            for (int j = 0; j < 3; j++) {
                short8 bf = *(const short8*)(Ws + ((hb + j) * 16 + l16) * 72 + ks * 32 + quad * 8);
                acc[j] = __builtin_amdgcn_mfma_f32_16x16x32_bf16(af, bf, acc[j], 0, 0, 0);
            }
        }
        __syncthreads();
    }
#pragma unroll
    for (int j = 0; j < 3; j++) {
        int hh = hb + j, m = hh >> 2, h4 = hh & 3;
        short* outp = (m == 0) ? qb : (m == 1) ? kb : vb;
#pragma unroll
        for (int r4 = 0; r4 < 4; r4++) {
            int t = t0 + quad * 4 + r4;
            outp[((long)(b * T_ + t)) * DH + h4 * 16 + l16] = f2bf(acc[j][r4]);
        }
    }
}

// ---------------- Kernel 2: column sums of exp(QK^T/8) — compact active-task grid ----------------
// grid = B*144: only active (strip st, chunk c) with c in [st>>2, 7]. R9 body unchanged.
// Also zeroes `out` (grid-strided, runs strictly before k_out's atomics).
__global__ __launch_bounds__(256, 4) void k_stats(
    const short* __restrict__ qb, const short* __restrict__ kb,
    float* __restrict__ lsum, float* __restrict__ out)
{
    __shared__ short Qb[128 * 72];   // 128 t-rows x (64+8 pad) shorts = 18432 B
    int tid = threadIdx.x;
    int lane = tid & 63, w = tid >> 6;
    int l16 = lane & 15, quad = lane >> 4;

    // fold-in: zero out (262144 f32x4 over 576 blocks, grid-strided with guard)
    {
        long idx = (long)blockIdx.x * 256 + tid;
        if (idx < 262144) *(f32x4*)(out + idx * 4) = (f32x4)(0.f);
        idx += (long)B_ * NTASK * 256;
        if (idx < 262144) *(f32x4*)(out + idx * 4) = (f32x4)(0.f);
    }

    int b = blockIdx.x / NTASK;
    int m = blockIdx.x - b * NTASK;
    int st = 0, chunk = 0;
    for (st = 0; st < 32; st++) {           // uniform scalar decode: count = 8-(st>>2)
        int cnt = 8 - (st >> 2);
        if (m < cnt) { chunk = (st >> 2) + m; break; }
        m -= cnt;
    }
    int c0 = chunk * CTS, cend = c0 + CTS;
    int s0blk = st * 128;
    int s0w = s0blk + w * 32;
    long bq = (long)b * T_ * DH;

    const short8* kp0 = (const short8*)(kb + bq + (long)(s0w + l16) * DH + quad * 8);
    short8 a00 = kp0[0], a01 = kp0[4];      // A[m=s][k=h], rows s0w..+15
    const short8* kp1 = (const short8*)(kb + bq + (long)(s0w + 16 + l16) * DH + quad * 8);
    short8 a10 = kp1[0], a11 = kp1[4];      // rows s0w+16..+31

    int t_lo = (c0 > s0blk) ? c0 : s0blk;   // block-uniform, multiple of 128
    int nsteps = (cend - t_lo) >> 7;
    float acc0[4] = {0.f, 0.f, 0.f, 0.f};
    float acc1[4] = {0.f, 0.f, 0.f, 0.f};

    for (int stp = 0; stp < nsteps; stp++) {
        int t0 = t_lo + stp * 128;
#pragma unroll
        for (int p = 0; p < 4; p++) {       // stage 128 q-rows, coalesced 16B/thread
            int idx = p * 256 + tid;
            int row = idx >> 3, col = idx & 7;
            *(short8*)(Qb + row * 72 + col * 8) =
                *(const short8*)(qb + bq + (long)(t0 + row) * DH + col * 8);
        }
        __syncthreads();
        for (int sub = 0; sub < 8; sub++) {
            int tt = t0 + sub * 16;
            if (tt + 15 >= s0w) {           // wave-uniform: tile not fully masked
                short8 b0 = *(const short8*)(Qb + (sub * 16 + l16) * 72 + quad * 8);
                short8 b1 = *(const short8*)(Qb + (sub * 16 + l16) * 72 + 32 + quad * 8);
                int t = tt + l16;
                f32x4 d0 = (f32x4)(0.f);
                d0 = __builtin_amdgcn_mfma_f32_16x16x32_bf16(a00, b0, d0, 0, 0, 0);
                d0 = __builtin_amdgcn_mfma_f32_16x16x32_bf16(a01, b1, d0, 0, 0, 0);
#pragma unroll
                for (int r = 0; r < 4; r++) {   // D: row=s, col=t
                    int s = s0w + quad * 4 + r;
                    float p = __expf(d0[r] * 0.125f);
                    acc0[r] += (t >= s) ? p : 0.f;
                }
                if (tt + 15 >= s0w + 16) {
                    f32x4 d1 = (f32x4)(0.f);
                    d1 = __builtin_amdgcn_mfma_f32_16x16x32_bf16(a10, b0, d1, 0, 0, 0);
                    d1 = __builtin_amdgcn_mfma_f32_16x16x32_bf16(a11, b1, d1, 0, 0, 0);
#pragma unroll
                    for (int r = 0; r < 4; r++) {
                        int s = s0w + 16 + quad * 4 + r;
                        float p = __expf(d1[r] * 0.125f);
                        acc1[r] += (t >= s) ? p : 0.f;
                    }
                }
            }
        }
        __syncthreads();
    }
#pragma unroll
    for (int r = 0; r < 4; r++) {
        float v = acc0[r];
        v += __shfl_xor(v, 1, 16); v += __shfl_xor(v, 2, 16);
        v += __shfl_xor(v, 4, 16); v += __shfl_xor(v, 8, 16);
        if (l16 == 0) atomicAdd(&lsum[b * T_ + s0w + quad * 4 + r], v);
        float v1 = acc1[r];
        v1 += __shfl_xor(v1, 1, 16); v1 += __shfl_xor(v1, 2, 16);
        v1 += __shfl_xor(v1, 4, 16); v1 += __shfl_xor(v1, 8, 16);
        if (l16 == 0) atomicAdd(&lsum[b * T_ + s0w + 16 + quad * 4 + r], v1);
    }
}

// ---------------- Kernel 3: vTc[b][s/16][h][s%16] = bf16(v[b][s][h] / lsum[s]) ----------------
__global__ __launch_bounds__(256) void k_vt(
    const short* __restrict__ vb, const float* __restrict__ lsum, short* __restrict__ vTc)
{
    int tid = threadIdx.x;
    int b = blockIdx.x >> 6;
    int s0 = (blockIdx.x & 63) * 64;
    int h = tid & 63, g = tid >> 6;
    long vbase = ((long)(b * T_) + s0 + g * 16) * DH + h;
    long lbase = (long)b * T_ + s0 + g * 16;
    short8 lo, hi;
#pragma unroll
    for (int k2 = 0; k2 < 8; k2++) {
        float rl = 1.0f / lsum[lbase + k2];
        lo[k2] = f2bf(bf2f(vb[vbase + (long)k2 * DH]) * rl);
        float rh = 1.0f / lsum[lbase + 8 + k2];
        hi[k2] = f2bf(bf2f(vb[vbase + (long)(8 + k2) * DH]) * rh);
    }
    long ob = ((long)(b * 256 + (s0 >> 4) + g) * 64 + h) * 16;
    *(short8*)(vTc + ob) = lo;
    *(short8*)(vTc + ob + 8) = hi;
}

// ---------------- Kernel 4: fused score+PV — compact active-task grid (R9 body) ----------------
// grid = B*144: only active (strip i, chunk c) with c <= i>>2, longest strips first.
// Swapped QK^T (D[s][t]): lane-local P feeds v_mfma_f32_16x16x16bf16_1k directly.
__global__ __launch_bounds__(256, 4) void k_out(
    const short* __restrict__ qb, const short* __restrict__ kb,
    const short* __restrict__ vTc, float* __restrict__ out)
{
    __shared__ short Kb[128 * 72];      // 128 s-rows x (64+8 pad) shorts = 18432 B
    int tid = threadIdx.x;
    int lane = tid & 63, w = tid >> 6;
    int l16 = lane & 15, quad = lane >> 4;
    int b = blockIdx.x / NTASK;
    int m = blockIdx.x - b * NTASK;
    int strip = 31, chunk = 0;
    for (strip = 31; strip >= 0; strip--) { // uniform scalar decode, longest-first
        int cnt = (strip >> 2) + 1;         // active chunks 0..strip>>2
        if (m < cnt) { chunk = m; break; }
        m -= cnt;
    }
    int c0 = chunk * CS;
    int blk_tmax = strip * 128 + 127;
    int s_hi = (c0 + CS < blk_tmax + 1) ? c0 + CS : blk_tmax + 1;
    int nsteps = (s_hi - c0 + 127) >> 7;
    int t0w = strip * 128 + w * 32;
    long bq = (long)b * T_ * DH;

    const short8* qp0 = (const short8*)(qb + bq + (long)(t0w + l16) * DH + quad * 8);
    short8 q00 = qp0[0], q01 = qp0[4];      // B[n=t][k=h], rows t0w..+15
    const short8* qp1 = (const short8*)(qb + bq + (long)(t0w + 16 + l16) * DH + quad * 8);
    short8 q10 = qp1[0], q11 = qp1[4];      // rows t0w+16..+31
    const short* vTb = vTc + (long)b * (T_ / 16) * DH * 16;

    f32x4 o0[4], o1[4];
#pragma unroll
    for (int i = 0; i < 4; i++) { o0[i] = (f32x4)(0.f); o1[i] = (f32x4)(0.f); }
    int t0 = t0w + l16, t1 = t0 + 16;

    for (int stp = 0; stp < nsteps; stp++) {
        int s0 = c0 + stp * 128;
        // stage K tile: 128 s-rows x 64 shorts, padded to 72
#pragma unroll
        for (int p = 0; p < 4; p++) {
            int idx = p * 256 + tid;
            int row = idx >> 3, col = idx & 7;
            *(short8*)(Kb + row * 72 + col * 8) =
                *(const short8*)(kb + bq + (long)(s0 + row) * DH + col * 8);
        }
        __syncthreads();

        for (int sub = 0; sub < 8; sub++) {
            int sc = s0 + sub * 16;
            if (sc > t0w + 31) break;       // wave-uniform: past this wave's diagonal
            short8 a0 = *(const short8*)(Kb + (sub * 16 + l16) * 72 + quad * 8);
            short8 a1 = *(const short8*)(Kb + (sub * 16 + l16) * 72 + 32 + quad * 8);
            // V fragments: independent of the MFMA chain — issue early
            const short* vc = vTb + (long)(sc >> 4) * 1024 + quad * 4;
            bf16x4 bv[4];
#pragma unroll
            for (int h4 = 0; h4 < 4; h4++)
                bv[h4] = *(const bf16x4*)(vc + (h4 * 16 + l16) * 16);  // B[n=h][k=s]

            // tile1 (t0w+16..31)
            f32x4 d1 = (f32x4)(0.f);
            d1 = __builtin_amdgcn_mfma_f32_16x16x32_bf16(a0, q10, d1, 0, 0, 0);
            d1 = __builtin_amdgcn_mfma_f32_16x16x32_bf16(a1, q11, d1, 0, 0, 0);
            bf16x4 pa1 = pmask4(d1, sc + quad * 4, t1);  // lane: P[t=l16][s=quad*4+j]

            bf16x4 pa0 = (bf16x4)(short)0;
            if (sc <= t0w + 15) {           // wave-uniform
                f32x4 d0 = (f32x4)(0.f);
                d0 = __builtin_amdgcn_mfma_f32_16x16x32_bf16(a0, q00, d0, 0, 0, 0);
                d0 = __builtin_amdgcn_mfma_f32_16x16x32_bf16(a1, q01, d0, 0, 0, 0);
                pa0 = pmask4(d0, sc + quad * 4, t0);
            }
#pragma unroll
            for (int h4 = 0; h4 < 4; h4++) {
                o1[h4] = __builtin_amdgcn_mfma_f32_16x16x16bf16_1k(pa1, bv[h4], o1[h4], 0, 0, 0);
                o0[h4] = __builtin_amdgcn_mfma_f32_16x16x16bf16_1k(pa0, bv[h4], o0[h4], 0, 0, 0);
            }
        }
        __syncthreads();
    }
#pragma unroll
    for (int h4 = 0; h4 < 4; h4++)
#pragma unroll
        for (int r = 0; r < 4; r++) {       // D: row=t (quad*4+r), col=h (l16)
            int t = t0w + quad * 4 + r;
            atomicAdd(&out[bq + (long)t * DH + h4 * 16 + l16], o0[h4][r]);
            atomicAdd(&out[bq + (long)(t + 16) * DH + h4 * 16 + l16], o1[h4][r]);
        }
}

extern "C" void kernel_launch(void* const* d_in, const int* in_sizes, int n_in,
                              void* d_out, int out_size, void* d_ws, size_t ws_size,
                              hipStream_t stream) {
    const float* x  = (const float*)d_in[0];
    const float* Wq = (const float*)d_in[1];
    const float* Wk = (const float*)d_in[2];
    const float* Wv = (const float*)d_in[3];
    float* out = (float*)d_out;

    char* ws = (char*)d_ws;
    short* qb   = (short*)(ws);                    // 2 MB  bf16 [B,T,64]
    short* kb   = (short*)(ws + (2l << 20));       // 2 MB  bf16 [B,T,64]
    short* vb   = (short*)(ws + (4l << 20));       // 2 MB  bf16 [B,T,64]
    short* vTc  = (short*)(ws + (6l << 20));       // 2 MB  bf16 [B,T/16,64,16]
    float* lsum = (float*)(ws + (8l << 20));       // 64 KB fp32 [B,T]

    // 4 dispatches, no memsets: k_proj zeroes lsum, k_stats zeroes out.
    k_proj<<<dim3(B_ * T_ / 16), dim3(256), 0, stream>>>(x, Wq, Wk, Wv, qb, kb, vb, lsum);
    k_stats<<<dim3(B_ * NTASK), dim3(256), 0, stream>>>(qb, kb, lsum, out);
    k_vt<<<dim3(B_ * T_ / 64), dim3(256), 0, stream>>>(vb, lsum, vTc);
    k_out<<<dim3(B_ * NTASK), dim3(256), 0, stream>>>(qb, kb, vTc, out);
}